// Round 8
// baseline (498.491 us; speedup 1.0000x reference)
//
#include <hip/hip_runtime.h>
#include <hip/hip_fp16.h>
#include <stdint.h>

// Problem constants (fixed: M=N=K=4096).
// Harness buffer reality (proven r5-r7): x,lut,out are float32; packed_weight
// is int32 holding ONE byte per element (hi nibble = even k, lo nibble = odd k).
#define M_DIM 4096
#define N_DIM 4096
#define K_DIM 4096
#define BM 128
#define BN 128
#define BK 32
#define NKT (K_DIM / BK)
#define KW (K_DIM / 2)

typedef _Float16 half8 __attribute__((ext_vector_type(8)));   // 4 VGPRs (MFMA A/B)
typedef float f32x4 __attribute__((ext_vector_type(4)));      // MFMA accumulator

__device__ __forceinline__ uint32_t pk2(float a, float b) {
  // packed f32->f16 RTZ (exact: every input value is fp16-representable)
  auto h = __builtin_amdgcn_cvt_pkrtz(a, b);  // a -> low halfword
  return __builtin_bit_cast(uint32_t, h);
}

// Dequant one packed byte -> u32 (fp16 even-k | fp16 odd-k << 16) via v_perm
// byte lookup in an 8-byte magnitude pool (fp16 high bytes of lut[0..7]; fp4
// values have zero fp16 low byte). Sign: lut[8..15] == -lut[0..7], so nibble
// bit 3 ORs into the fp16 sign bit.  [proven bit-exact r6/r7]
__device__ __forceinline__ uint32_t dq(uint32_t b, uint32_t ph, uint32_t pl) {
#if __has_builtin(__builtin_amdgcn_perm)
  const uint32_t sel = ((b & 0x70u) << 4) | ((b & 0x07u) << 24);
  uint32_t v = __builtin_amdgcn_perm(ph, pl, sel);  // bytes 4-7 = ph, 0-3 = pl
#else
  const uint64_t pool = ((uint64_t)ph << 32) | pl;
  const uint32_t mh = (uint32_t)(pool >> (((b >> 4) & 7u) * 8)) & 0xFFu;
  const uint32_t ml = (uint32_t)(pool >> ((b & 7u) * 8)) & 0xFFu;
  uint32_t v = (mh << 8) | (ml << 24);
#endif
  const uint32_t sg = ((b & 0x88u) * 0x10000100u) & 0x80008000u;  // b7->15, b3->31
  return v | sg;
}

// 4 packed words (one int4 = 8 weights along k) -> one MFMA B-fragment.
// Element e of the half8 corresponds to k = quad*8 + e, matching the A-side.
__device__ __forceinline__ half8 dq4(const int4 w, uint32_t ph, uint32_t pl) {
  const uint4 u = make_uint4(dq(w.x, ph, pl), dq(w.y, ph, pl),
                             dq(w.z, ph, pl), dq(w.w, ph, pl));
  return __builtin_bit_cast(half8, u);
}

// Pre-pass: x f32 [M,K] -> fp16 bits in d_ws. 2 float4 in, 1 uint4 out/thread.
__global__ __launch_bounds__(256) void cvt_x_kernel(const float4* __restrict__ xin,
                                                    uint4* __restrict__ xout) {
  const int i = blockIdx.x * 256 + threadIdx.x;   // uint4 index
  const float4 v0 = xin[2 * i];
  const float4 v1 = xin[2 * i + 1];
  xout[i] = make_uint4(pk2(v0.x, v0.y), pk2(v0.z, v0.w),
                       pk2(v1.x, v1.y), pk2(v1.z, v1.w));
}

// y[m][n] = sum_k x[m][k] * W[n][k]; W dequantized from packed fp4 via LUT.
// 128x128 tile, BK=32, 4 waves (2x2), 4x4 grid of 16x16x32 f16 MFMA per wave.
// Round 8: B never touches LDS — each lane's int4 load of packed words IS its
// B-fragment after perm-dequant. B loads for kt+1 issue after the draining
// barrier and fly during MFMA(kt). A stays on the proven GLL path.
__global__ __launch_bounds__(256, 2) void fp4gemm_kernel(
    const uint8_t* __restrict__ xh,    // fp16 bits [M, K] (in d_ws)
    const int* __restrict__ pw,        // [N, K/2] int32, one packed byte each
    const float* __restrict__ lutf,    // 16 float LUT values
    float* __restrict__ out)           // [M, N] float32
{
  __shared__ uint16_t ldsA[BM * BK];   // [128][32] fp16 (contiguous for GLL)

  const int tid  = threadIdx.x;
  const int lane = tid & 63;
  const int wave = tid >> 6;
  const int wm   = wave >> 1;          // 64-row half of M tile
  const int wn   = wave & 1;           // 64-col half of N tile
  const int m0 = blockIdx.y * BM;
  const int n0 = blockIdx.x * BN;

  // Magnitude pool from runtime LUT (fp16 high bytes of lut[0..7]).
  const uint32_t h01 = pk2(lutf[0], lutf[1]);
  const uint32_t h23 = pk2(lutf[2], lutf[3]);
  const uint32_t h45 = pk2(lutf[4], lutf[5]);
  const uint32_t h67 = pk2(lutf[6], lutf[7]);
#if __has_builtin(__builtin_amdgcn_perm)
  const uint32_t pl = __builtin_amdgcn_perm(h23, h01, 0x07050301u);
  const uint32_t ph = __builtin_amdgcn_perm(h67, h45, 0x07050301u);
#else
  const uint32_t pl = ((h01 >> 8) & 0xFFu) | ((h01 >> 24) << 8) |
                      (((h23 >> 8) & 0xFFu) << 16) | ((h23 >> 24) << 24);
  const uint32_t ph = ((h45 >> 8) & 0xFFu) | ((h45 >> 24) << 8) |
                      (((h67 >> 8) & 0xFFu) << 16) | ((h67 >> 24) << 24);
#endif

  f32x4 acc[4][4];
#pragma unroll
  for (int i = 0; i < 4; ++i)
#pragma unroll
    for (int j = 0; j < 4; ++j) acc[i][j] = (f32x4){0.f, 0.f, 0.f, 0.f};

  // B-fragment addressing: lane covers n = n0 + wn*64 + j*16 + (lane&15),
  // k-quad = lane>>4 -> 4 consecutive packed words starting at quad*4.
  const int nr  = n0 + wn * 64 + (lane & 15);
  const int kq4 = (lane >> 4) * 4;
  const int* pwb = pw + (size_t)nr * KW + kq4;   // + j*16*KW + kt*16

  // Preload B words for kt = 0.
  int4 wreg[4];
#pragma unroll
  for (int j = 0; j < 4; ++j)
    wreg[j] = *(const int4*)(pwb + (size_t)j * 16 * KW);

  for (int kt = 0; kt < NKT; ++kt) {
    __syncthreads();  // all waves done reading ldsA(kt-1)

    // ---- Stage A: 128x32 fp16 = 8 KB via global_load_lds, 16 B/lane ----
#pragma unroll
    for (int s = 0; s < 2; ++s) {
      const int idx = tid + s * 256;        // 0..511 16B chunks
      const int row = idx >> 2;             // 64 B per A row
      const int c16 = idx & 3;
      const uint8_t* gp = xh + ((size_t)(m0 + row) * K_DIM + kt * BK) * 2 + c16 * 16;
      uint8_t* lp = (uint8_t*)ldsA + (size_t)idx * 16;  // = wave base + lane*16
      __builtin_amdgcn_global_load_lds(
          (const __attribute__((address_space(1))) uint32_t*)gp,
          (__attribute__((address_space(3))) uint32_t*)lp, 16, 0, 0);
    }

    // ---- Dequant current B words -> fragments (VALU, covers GLL flight) ----
    half8 bfr[4];
#pragma unroll
    for (int j = 0; j < 4; ++j) bfr[j] = dq4(wreg[j], ph, pl);

    __syncthreads();  // drains GLL writes into ldsA (and prior B prefetch)

    // ---- Prefetch B words for kt+1: in flight during the MFMAs below ----
    const int ktn = (kt + 1 < NKT) ? kt + 1 : kt;
#pragma unroll
    for (int j = 0; j < 4; ++j)
      wreg[j] = *(const int4*)(pwb + (size_t)j * 16 * KW + ktn * 16);

    // ---- A fragments + 16 MFMAs ----
    half8 af[4];
#pragma unroll
    for (int i = 0; i < 4; ++i) {
      const uint16_t* pa = ldsA + (wm * 64 + i * 16 + (lane & 15)) * BK + (lane >> 4) * 8;
      af[i] = *(const half8*)pa;
    }
#pragma unroll
    for (int i = 0; i < 4; ++i)
#pragma unroll
      for (int j = 0; j < 4; ++j)
        acc[i][j] = __builtin_amdgcn_mfma_f32_16x16x32_f16(af[i], bfr[j], acc[i][j], 0, 0, 0);
  }

  // ---- Epilogue: C/D layout col(n) = lane&15, row(m) = (lane>>4)*4 + reg ----
  const int mb = m0 + wm * 64 + (lane >> 4) * 4;
  const int nb = n0 + wn * 64 + (lane & 15);
#pragma unroll
  for (int i = 0; i < 4; ++i)
#pragma unroll
    for (int j = 0; j < 4; ++j)
#pragma unroll
      for (int r = 0; r < 4; ++r)
        out[(size_t)(mb + i * 16 + r) * N_DIM + (nb + j * 16)] = acc[i][j][r];
}

extern "C" void kernel_launch(void* const* d_in, const int* in_sizes, int n_in,
                              void* d_out, int out_size, void* d_ws, size_t ws_size,
                              hipStream_t stream) {
  // Size-based dispatch (element counts are dtype-independent and unique).
  const void* px = nullptr; const void* ppw = nullptr; const void* plut = nullptr;
  for (int i = 0; i < n_in; ++i) {
    const long s = in_sizes[i];
    if (s == (long)M_DIM * K_DIM) px = d_in[i];
    else if (s == (long)N_DIM * KW) ppw = d_in[i];
    else if (s == 16) plut = d_in[i];
  }
  if (!px || !ppw || !plut) { px = d_in[0]; ppw = d_in[1]; plut = d_in[2]; }

  dim3 grid(N_DIM / BN, M_DIM / BM);  // (32, 32)

  // x f32 -> fp16 into ws (32 MB), then GEMM staged from ws via GLL.
  cvt_x_kernel<<<(M_DIM * K_DIM / 8) / 256, 256, 0, stream>>>(
      (const float4*)px, (uint4*)d_ws);
  fp4gemm_kernel<<<grid, dim3(256), 0, stream>>>(
      (const uint8_t*)d_ws, (const int*)ppw, (const float*)plut, (float*)d_out);
}

// Round 9
// 298.245 us; speedup vs baseline: 1.6714x; 1.6714x over previous
//
#include <hip/hip_runtime.h>
#include <hip/hip_fp16.h>
#include <stdint.h>

// Problem constants (fixed: M=N=K=4096).
// Harness buffer reality (proven r5-r8): x,lut,out are float32; packed_weight
// is int32 holding ONE byte per element (hi nibble = even k, lo nibble = odd k).
#define M_DIM 4096
#define N_DIM 4096
#define K_DIM 4096
#define BM 128
#define BN 128
#define BK 32
#define KW (K_DIM / 2)

typedef _Float16 half8 __attribute__((ext_vector_type(8)));   // 4 VGPRs (MFMA A/B)
typedef float f32x4 __attribute__((ext_vector_type(4)));      // MFMA accumulator

__device__ __forceinline__ uint32_t pk2(float a, float b) {
  // packed f32->f16 RTZ (exact: every input value is fp16-representable)
  auto h = __builtin_amdgcn_cvt_pkrtz(a, b);  // a -> low halfword
  return __builtin_bit_cast(uint32_t, h);
}

// Dequant one packed byte -> u32 (fp16 even-k | fp16 odd-k << 16) via v_perm
// byte lookup in an 8-byte magnitude pool (fp16 high bytes of lut[0..7]; fp4
// values have zero fp16 low byte). Sign: lut[8..15] == -lut[0..7], nibble
// bit 3 ORs into the fp16 sign bit.  [proven bit-exact r6-r8]
__device__ __forceinline__ uint32_t dq(uint32_t b, uint32_t ph, uint32_t pl) {
#if __has_builtin(__builtin_amdgcn_perm)
  const uint32_t sel = ((b & 0x70u) << 4) | ((b & 0x07u) << 24);
  uint32_t v = __builtin_amdgcn_perm(ph, pl, sel);  // bytes 4-7 = ph, 0-3 = pl
#else
  const uint64_t pool = ((uint64_t)ph << 32) | pl;
  const uint32_t mh = (uint32_t)(pool >> (((b >> 4) & 7u) * 8)) & 0xFFu;
  const uint32_t ml = (uint32_t)(pool >> ((b & 7u) * 8)) & 0xFFu;
  uint32_t v = (mh << 8) | (ml << 24);
#endif
  const uint32_t sg = ((b & 0x88u) * 0x10000100u) & 0x80008000u;  // b7->15, b3->31
  return v | sg;
}

// Pre-pass: x f32 [M,K] -> fp16 bits in d_ws. 2 float4 in, 1 uint4 out/thread.
__global__ __launch_bounds__(256) void cvt_x_kernel(const float4* __restrict__ xin,
                                                    uint4* __restrict__ xout) {
  const int i = blockIdx.x * 256 + threadIdx.x;   // uint4 index
  const float4 v0 = xin[2 * i];
  const float4 v1 = xin[2 * i + 1];
  xout[i] = make_uint4(pk2(v0.x, v0.y), pk2(v0.z, v0.w),
                       pk2(v1.x, v1.y), pk2(v1.z, v1.w));
}

// y[m][n] = sum_k x[m][k] * W[n][k]; W dequantized from packed fp4 via LUT.
// 128x128 tile, BK=32, 4 waves (2x2), 4x4 grid of 16x16x32 f16 MFMA per wave.
// Round 9 = r7 (206us champion) + XOR bank swizzle: 16B chunk c of row r holds
// k-chunk (c ^ ((r>>1)&3)). Frag reads go 8-way -> 2-way (free); B writes go
// 2x-min -> min passes. GLL source-permute keeps the LDS dest contiguous.
__global__ __launch_bounds__(256, 2) void fp4gemm_kernel(
    const uint8_t* __restrict__ xh,    // fp16 bits [M, K] (in d_ws)
    const int* __restrict__ pw,        // [N, K/2] int32, one packed byte each
    const float* __restrict__ lutf,    // 16 float LUT values
    float* __restrict__ out)           // [M, N] float32
{
  __shared__ uint16_t ldsA[BM * BK];   // [128][32] fp16, swizzled chunks
  __shared__ uint16_t ldsB[BN * BK];   // [128][32] fp16, swizzled chunks

  const int tid  = threadIdx.x;
  const int lane = tid & 63;
  const int wave = tid >> 6;
  const int wm   = wave >> 1;          // 64-row half of M tile
  const int wn   = wave & 1;           // 64-col half of N tile
  const int m0 = blockIdx.y * BM;
  const int n0 = blockIdx.x * BN;

  // Magnitude pool from runtime LUT (fp16 high bytes of lut[0..7]).
  const uint32_t h01 = pk2(lutf[0], lutf[1]);
  const uint32_t h23 = pk2(lutf[2], lutf[3]);
  const uint32_t h45 = pk2(lutf[4], lutf[5]);
  const uint32_t h67 = pk2(lutf[6], lutf[7]);
#if __has_builtin(__builtin_amdgcn_perm)
  const uint32_t pl = __builtin_amdgcn_perm(h23, h01, 0x07050301u);
  const uint32_t ph = __builtin_amdgcn_perm(h67, h45, 0x07050301u);
#else
  const uint32_t pl = ((h01 >> 8) & 0xFFu) | ((h01 >> 24) << 8) |
                      (((h23 >> 8) & 0xFFu) << 16) | ((h23 >> 24) << 24);
  const uint32_t ph = ((h45 >> 8) & 0xFFu) | ((h45 >> 24) << 8) |
                      (((h67 >> 8) & 0xFFu) << 16) | ((h67 >> 24) << 24);
#endif

  f32x4 acc[4][4];
#pragma unroll
  for (int i = 0; i < 4; ++i)
#pragma unroll
    for (int j = 0; j < 4; ++j) acc[i][j] = (f32x4){0.f, 0.f, 0.f, 0.f};

  // B staging: thread t -> row (n) = t>>1, half-row = t&1 (8 packed words)
  const int rowB  = tid >> 1;
  const int halfB = tid & 1;
  const int swzB  = (rowB >> 1) & 3;   // row's chunk-XOR key

  for (int kt = 0; kt < K_DIM / BK; ++kt) {
    __syncthreads();  // prev compute done before LDS overwrite

    // ---- Stage A: 128x32 fp16 = 8 KB via global_load_lds, 16 B/lane ----
    // LDS slot (row, c16) receives global k-chunk (c16 ^ ((row>>1)&3)).
#pragma unroll
    for (int s = 0; s < 2; ++s) {
      const int idx = tid + s * 256;        // 0..511 16B slots (contiguous/wave)
      const int row = idx >> 2;
      const int c16 = idx & 3;
      const int g16 = c16 ^ ((row >> 1) & 3);
      const uint8_t* gp = xh + ((size_t)(m0 + row) * K_DIM + kt * BK) * 2 + g16 * 16;
      uint8_t* lp = (uint8_t*)ldsA + (size_t)idx * 16;  // = wave base + lane*16
      __builtin_amdgcn_global_load_lds(
          (const __attribute__((address_space(1))) uint32_t*)gp,
          (__attribute__((address_space(3))) uint32_t*)lp, 16, 0, 0);
    }

    // ---- Stage B: 8 packed words -> 16 weights, two swizzled 16B stores ----
    {
      const int* gp = pw + (size_t)(n0 + rowB) * KW + kt * (BK / 2) + halfB * 8;
      const int4 wA = ((const int4*)gp)[0];   // k-chunk halfB*2 + 0
      const int4 wB = ((const int4*)gp)[1];   // k-chunk halfB*2 + 1
      uint8_t* base = (uint8_t*)ldsB + rowB * 64;
      *(uint4*)(base + ((halfB * 2 + 0) ^ swzB) * 16) =
          make_uint4(dq(wA.x, ph, pl), dq(wA.y, ph, pl),
                     dq(wA.z, ph, pl), dq(wA.w, ph, pl));
      *(uint4*)(base + ((halfB * 2 + 1) ^ swzB) * 16) =
          make_uint4(dq(wB.x, ph, pl), dq(wB.y, ph, pl),
                     dq(wB.z, ph, pl), dq(wB.w, ph, pl));
    }

    __syncthreads();  // drains vmcnt (GLL) + lgkm (B writes)

    // ---- Compute: 4 A-frags x 4 B-frags, 16 MFMAs ----
    // Frag (row, q) lives at chunk q ^ ((row>>1)&3).
    const int q = lane >> 4;
    half8 af[4], bfr[4];
#pragma unroll
    for (int i = 0; i < 4; ++i) {
      const int row = wm * 64 + i * 16 + (lane & 15);
      const uint16_t* pa = ldsA + row * BK + (q ^ ((row >> 1) & 3)) * 8;
      af[i] = *(const half8*)pa;
    }
#pragma unroll
    for (int j = 0; j < 4; ++j) {
      const int row = wn * 64 + j * 16 + (lane & 15);
      const uint16_t* pb = ldsB + row * BK + (q ^ ((row >> 1) & 3)) * 8;
      bfr[j] = *(const half8*)pb;
    }
#pragma unroll
    for (int i = 0; i < 4; ++i)
#pragma unroll
      for (int j = 0; j < 4; ++j)
        acc[i][j] = __builtin_amdgcn_mfma_f32_16x16x32_f16(af[i], bfr[j], acc[i][j], 0, 0, 0);
  }

  // ---- Epilogue: C/D layout col(n) = lane&15, row(m) = (lane>>4)*4 + reg ----
  const int mb = m0 + wm * 64 + (lane >> 4) * 4;
  const int nb = n0 + wn * 64 + (lane & 15);
#pragma unroll
  for (int i = 0; i < 4; ++i)
#pragma unroll
    for (int j = 0; j < 4; ++j)
#pragma unroll
      for (int r = 0; r < 4; ++r)
        out[(size_t)(mb + i * 16 + r) * N_DIM + (nb + j * 16)] = acc[i][j][r];
}

extern "C" void kernel_launch(void* const* d_in, const int* in_sizes, int n_in,
                              void* d_out, int out_size, void* d_ws, size_t ws_size,
                              hipStream_t stream) {
  // Size-based dispatch (element counts are dtype-independent and unique).
  const void* px = nullptr; const void* ppw = nullptr; const void* plut = nullptr;
  for (int i = 0; i < n_in; ++i) {
    const long s = in_sizes[i];
    if (s == (long)M_DIM * K_DIM) px = d_in[i];
    else if (s == (long)N_DIM * KW) ppw = d_in[i];
    else if (s == 16) plut = d_in[i];
  }
  if (!px || !ppw || !plut) { px = d_in[0]; ppw = d_in[1]; plut = d_in[2]; }

  dim3 grid(N_DIM / BN, M_DIM / BM);  // (32, 32)

  // x f32 -> fp16 into ws (32 MB), then GEMM staged from ws via GLL.
  cvt_x_kernel<<<(M_DIM * K_DIM / 8) / 256, 256, 0, stream>>>(
      (const float4*)px, (uint4*)d_ws);
  fp4gemm_kernel<<<grid, dim3(256), 0, stream>>>(
      (const uint8_t*)d_ws, (const int*)ppw, (const float*)plut, (float*)d_out);
}